// Round 6
// baseline (206.080 us; speedup 1.0000x reference)
//
#include <hip/hip_runtime.h>
#include <hip/hip_bf16.h>

typedef __attribute__((ext_vector_type(4))) float f32x4;
typedef __attribute__((ext_vector_type(8))) short bf16x8;

__device__ __forceinline__ void gload_lds16(const void* g, void* l) {
  __builtin_amdgcn_global_load_lds(
      (const __attribute__((address_space(1))) void*)g,
      (__attribute__((address_space(3))) void*)l, 16, 0, 0);
}

__device__ __forceinline__ unsigned short f2bf(float f) {
  union { float f; unsigned u; } x; x.f = f;
  unsigned r = x.u + 0x7fffu + ((x.u >> 16) & 1u);
  return (unsigned short)(r >> 16);
}

__device__ __forceinline__ float bf2f(unsigned short s) {
  union { unsigned u; float f; } x; x.u = (unsigned)s << 16;
  return x.f;
}

template<int N> __device__ __forceinline__ void vm_wait();
template<> __device__ __forceinline__ void vm_wait<0>() { asm volatile("s_waitcnt vmcnt(0)" ::: "memory"); }
template<> __device__ __forceinline__ void vm_wait<4>() { asm volatile("s_waitcnt vmcnt(4)" ::: "memory"); }
template<> __device__ __forceinline__ void vm_wait<6>() { asm volatile("s_waitcnt vmcnt(6)" ::: "memory"); }

#define BARRIER() asm volatile("s_barrier" ::: "memory")
#define SCHED0()  __builtin_amdgcn_sched_barrier(0)

// ---------------------------------------------------------------------------
// 256xBN 8-phase double-buffered GEMM: C = f(alpha * A[M][K] @ Bt[N][K]^T)
// EPI: 0 = alpha only,
//      3 = exp(alpha*(acc + bias[bz*2048+col])) + atomic per-row sum into rs,
//      5 = acc * rcp(rs[row]) + bias[col].
// 512 threads, BK=64, T1 XCD swizzle, T2 LDS swizzle, T4 counted vmcnt, T5.
// ---------------------------------------------------------------------------
template<int BN, int EPI, bool OUT_F32>
__global__ __launch_bounds__(512, 2)
void gemm256(const unsigned short* __restrict__ A,
             const unsigned short* __restrict__ Bt,
             const float* __restrict__ bias,
             float* __restrict__ rs,
             void* __restrict__ Cout,
             int K, int lda, int ldb, int ldc, float alpha,
             long sA, long sB, long sC)
{
  constexpr int THREADS = 512;
  constexpr int WN = BN / 64;          // waves along N (4 or 2)
  constexpr int WM = 8 / WN;           // waves along M (2 or 4)
  constexpr int WTM = 256 / WM;        // wave M extent (128 or 64)
  constexpr int M_REP = WTM / 16;      // 8 or 4
  constexpr int MH = M_REP / 2;        // 4 or 2
  constexpr int ABUFE = 256 * 64;
  constexpr int BBUFE = BN * 64;
  constexpr int BBASE = 2 * ABUFE;
  constexpr int LOADS_A = 2;
  constexpr int LOADS_B = BN / 128;
  constexpr int VM_STEADY = 2 * LOADS_B + LOADS_A;  // 6 or 4

  __shared__ __attribute__((aligned(16))) unsigned short lds[BBASE + 2 * BBUFE];

  // bijective XCD-chunked swizzle
  const int gx = gridDim.x, gy = gridDim.y;
  const int lid = blockIdx.x + gx * (blockIdx.y + gy * blockIdx.z);
  const int nwg = gx * gy * gridDim.z;
  const int q = nwg >> 3, r = nwg & 7;
  const int xcd = lid & 7, idx = lid >> 3;
  const int nl = (xcd < r ? xcd * (q + 1) : r * (q + 1) + (xcd - r) * q) + idx;
  const int bx = nl % gx, by = (nl / gx) % gy, bz = nl / (gx * gy);

  const int tid = threadIdx.x, wave = tid >> 6, lane = tid & 63;
  const int wr = wave / WN, wc = wave % WN;
  const int fr = lane & 15, fq = lane >> 4, sw = fr & 7;

  A  += (size_t)bz * sA;
  Bt += (size_t)bz * sB;
  const int m0 = by * 256;
  const int n0 = bx * BN;
  const int NT = K >> 6;

  f32x4 acc[M_REP][4] = {};
  bf16x8 a[MH][2], b[4][2];

  auto stageA = [&](int t, int half) {
#pragma unroll
    for (int c = 0; c < LOADS_A; ++c) {
      const int s = c * THREADS + tid;
      const int rr = s >> 3;
      const int col = ((tid & 7) ^ (rr & 7)) * 8;
      gload_lds16(A + (size_t)(m0 + half * 128 + rr) * lda + t * 64 + col,
                  &lds[(t & 1) * ABUFE + half * (128 * 64) + s * 8]);
    }
  };
  auto stageB = [&](int t, int half) {
#pragma unroll
    for (int c = 0; c < LOADS_B; ++c) {
      const int s = c * THREADS + tid;
      const int rr = s >> 3;
      const int col = ((tid & 7) ^ (rr & 7)) * 8;
      gload_lds16(Bt + (size_t)(n0 + half * (BN / 2) + rr) * ldb + t * 64 + col,
                  &lds[BBASE + (t & 1) * BBUFE + half * ((BN / 2) * 64) + s * 8]);
    }
  };
  auto readA = [&](int buf, int mq) {
    const unsigned short* p = &lds[buf * ABUFE];
#pragma unroll
    for (int mm = 0; mm < MH; ++mm)
#pragma unroll
      for (int kk = 0; kk < 2; ++kk)
        a[mm][kk] = *(const bf16x8*)(p + (wr * WTM + mq * (WTM / 2) + mm * 16 + fr) * 64
                                       + ((kk * 4 + fq) ^ sw) * 8);
  };
  auto readB = [&](int buf, int nh) {
    const unsigned short* p = &lds[BBASE + buf * BBUFE];
#pragma unroll
    for (int nn = 0; nn < 2; ++nn)
#pragma unroll
      for (int kk = 0; kk < 2; ++kk)
        b[nh * 2 + nn][kk] = *(const bf16x8*)(p + (wc * 64 + (nh * 2 + nn) * 16 + fr) * 64
                                                + ((kk * 4 + fq) ^ sw) * 8);
  };
  auto mfmaQ = [&](int mq, int nh) {
    __builtin_amdgcn_s_setprio(1);
#pragma unroll
    for (int kk = 0; kk < 2; ++kk)
#pragma unroll
      for (int mm = 0; mm < MH; ++mm)
#pragma unroll
        for (int nn = 0; nn < 2; ++nn)
          acc[mq * MH + mm][nh * 2 + nn] = __builtin_amdgcn_mfma_f32_16x16x32_bf16(
              a[mm][kk], b[nh * 2 + nn][kk], acc[mq * MH + mm][nh * 2 + nn], 0, 0, 0);
    __builtin_amdgcn_s_setprio(0);
  };

  // prologue: tile0 fully, tile1 {B0,B1,A0}
  stageA(0, 0); stageA(0, 1); stageB(0, 0); stageB(0, 1);
  if (NT > 1) { stageB(1, 0); stageB(1, 1); stageA(1, 0); vm_wait<VM_STEADY>(); }
  else        { vm_wait<0>(); }
  BARRIER();

  for (int t = 0; t < NT; ++t) {
    const int buf = t & 1;
    // ph1
    readA(buf, 0); readB(buf, 0);
    BARRIER(); SCHED0();
    mfmaQ(0, 0);
    SCHED0();
    BARRIER();
    // ph2
    readB(buf, 1);
    if (t + 1 < NT) stageA(t + 1, 1);
    BARRIER(); SCHED0();
    mfmaQ(0, 1);
    SCHED0();
    BARRIER();
    // ph3
    readA(buf, 1);
    if (t + 2 < NT) stageB(t + 2, 0);
    BARRIER(); SCHED0();
    mfmaQ(1, 0);
    SCHED0();
    BARRIER();
    // ph4
    if (t + 2 < NT) { stageB(t + 2, 1); stageA(t + 2, 0); vm_wait<VM_STEADY>(); }
    else            { vm_wait<0>(); }
    BARRIER(); SCHED0();
    mfmaQ(1, 1);
    SCHED0();
    BARRIER();
  }

  // epilogue (nn innermost for L2 write combining)
  float bvc[4];
  if (EPI == 5) {
#pragma unroll
    for (int nn = 0; nn < 4; ++nn) bvc[nn] = bias[n0 + wc * 64 + nn * 16 + fr];
  }
  if (EPI == 3) {
#pragma unroll
    for (int nn = 0; nn < 4; ++nn)
      bvc[nn] = bias[(size_t)bz * 2048 + n0 + wc * 64 + nn * 16 + fr];
  }
#pragma unroll
  for (int mm = 0; mm < M_REP; ++mm) {
    const int rbase = m0 + wr * WTM + mm * 16 + fq * 4;
#pragma unroll
    for (int j = 0; j < 4; ++j) {
      const int row = rbase + j;
      float rsc = 1.f;
      if (EPI == 5) rsc = __builtin_amdgcn_rcpf(rs[(size_t)bz * 2048 + row]);
      float part = 0.f;
#pragma unroll
      for (int nn = 0; nn < 4; ++nn) {
        const int col = n0 + wc * 64 + nn * 16 + fr;
        float v = acc[mm][nn][j];
        if      (EPI == 3) { v = __expf((v + bvc[nn]) * alpha); part += v; }
        else if (EPI == 5) v = v * rsc + bvc[nn];
        else               v = v * alpha;
        const size_t off = (size_t)bz * sC + (size_t)row * ldc + col;
        if (OUT_F32) ((float*)Cout)[off] = v;
        else         ((unsigned short*)Cout)[off] = f2bf(v);
      }
      if (EPI == 3) {
        part += __shfl_xor(part, 1); part += __shfl_xor(part, 2);
        part += __shfl_xor(part, 4); part += __shfl_xor(part, 8);
        if (fr == 0) atomicAdd(rs + (size_t)bz * 2048 + row, part);
      }
    }
  }
}

// ---------------------------------------------------------------------------
// prep GEMM: computes BOTH Mt = W2b @ W1b^T and W34 = W4t @ W3b^T (fp32,
// split-K x4 atomic). z: which = z>>2, slice = z&3. 128^2 tile, BK=32.
// ---------------------------------------------------------------------------
__global__ __launch_bounds__(256, 2)
void prep_gemm(const unsigned short* __restrict__ W2b, const unsigned short* __restrict__ W1b,
               const unsigned short* __restrict__ W4t, const unsigned short* __restrict__ W3b,
               float* __restrict__ MWf)
{
  __shared__ __attribute__((aligned(16))) unsigned short As[128 * 32];
  __shared__ __attribute__((aligned(16))) unsigned short Bs[128 * 32];
  const int which = blockIdx.z >> 2, slice = blockIdx.z & 3;
  const unsigned short* A  = which ? W4t : W2b;
  const unsigned short* Bt = which ? W3b : W1b;
  float* C = MWf + which * 1048576;

  const int tid = threadIdx.x, wave = tid >> 6, lane = tid & 63;
  const int m0 = blockIdx.y * 128, n0 = blockIdx.x * 128;
  f32x4 acc[4][4] = {};
  const int wr = wave >> 1, wc = wave & 1;
  const int fr = lane & 15, fq = lane >> 4;
  const int si0 = wave * 2, sr = lane >> 2, sce = (lane & 3) * 8;

  const int kbeg = slice * 256;
  for (int k0 = kbeg; k0 < kbeg + 256; k0 += 32) {
#pragma unroll
    for (int c = 0; c < 2; ++c) {
      const int i = si0 + c, rr = i * 16 + sr;
      gload_lds16(A  + (size_t)(m0 + rr) * 1024 + k0 + sce, As + i * 512 + lane * 8);
      gload_lds16(Bt + (size_t)(n0 + rr) * 1024 + k0 + sce, Bs + i * 512 + lane * 8);
    }
    __syncthreads();
    bf16x8 af[4], bg[4];
#pragma unroll
    for (int m = 0; m < 4; ++m)
      af[m] = *(const bf16x8*)(As + (wr * 64 + m * 16 + fr) * 32 + fq * 8);
#pragma unroll
    for (int n = 0; n < 4; ++n)
      bg[n] = *(const bf16x8*)(Bs + (wc * 64 + n * 16 + fr) * 32 + fq * 8);
#pragma unroll
    for (int m = 0; m < 4; ++m)
#pragma unroll
      for (int n = 0; n < 4; ++n)
        acc[m][n] = __builtin_amdgcn_mfma_f32_16x16x32_bf16(af[m], bg[n], acc[m][n], 0, 0, 0);
    __syncthreads();
  }
#pragma unroll
  for (int n = 0; n < 4; ++n) {
    const int col = n0 + wc * 64 + n * 16 + fr;
#pragma unroll
    for (int m = 0; m < 4; ++m) {
      const int rbase = m0 + wr * 64 + m * 16 + fq * 4;
#pragma unroll
      for (int j = 0; j < 4; ++j)
        atomicAdd(C + (size_t)(rbase + j) * 1024 + col, acc[m][n][j]);
    }
  }
}

// ---------------------------------------------------------------------------
// fp32 -> bf16 straight convert, 2048 elements per block
__global__ __launch_bounds__(256)
void convert_kernel(const float* __restrict__ x, unsigned short* __restrict__ xb)
{
  const int idx = (blockIdx.x * 256 + threadIdx.x) * 8;
  const float4 a = *(const float4*)(x + idx);
  const float4 b = *(const float4*)(x + idx + 4);
  unsigned u0 = (unsigned)f2bf(a.x) | ((unsigned)f2bf(a.y) << 16);
  unsigned u1 = (unsigned)f2bf(a.z) | ((unsigned)f2bf(a.w) << 16);
  unsigned u2 = (unsigned)f2bf(b.x) | ((unsigned)f2bf(b.y) << 16);
  unsigned u3 = (unsigned)f2bf(b.z) | ((unsigned)f2bf(b.w) << 16);
  uint4 o; o.x = u0; o.y = u1; o.z = u2; o.w = u3;
  *(uint4*)(xb + idx) = o;
}

// three 1024x1024 fp32 -> bf16 converts in one launch
__global__ __launch_bounds__(256)
void convert3_kernel(const float* __restrict__ a, const float* __restrict__ b,
                     const float* __restrict__ c,
                     unsigned short* __restrict__ oa, unsigned short* __restrict__ ob,
                     unsigned short* __restrict__ oc)
{
  const float* src = (blockIdx.y == 0) ? a : (blockIdx.y == 1) ? b : c;
  unsigned short* dst = (blockIdx.y == 0) ? oa : (blockIdx.y == 1) ? ob : oc;
  const int idx = (blockIdx.x * 256 + threadIdx.x) * 8;
  const float4 p = *(const float4*)(src + idx);
  const float4 q = *(const float4*)(src + idx + 4);
  unsigned u0 = (unsigned)f2bf(p.x) | ((unsigned)f2bf(p.y) << 16);
  unsigned u1 = (unsigned)f2bf(p.z) | ((unsigned)f2bf(p.w) << 16);
  unsigned u2 = (unsigned)f2bf(q.x) | ((unsigned)f2bf(q.y) << 16);
  unsigned u3 = (unsigned)f2bf(q.z) | ((unsigned)f2bf(q.w) << 16);
  uint4 o; o.x = u0; o.y = u1; o.z = u2; o.w = u3;
  *(uint4*)(dst + idx) = o;
}

// W4 fp32 [1024][1024] (j-major) -> W4t bf16 [1024][1024] (e-major)
__global__ __launch_bounds__(256)
void transpose_w4_kernel(const float* __restrict__ W, unsigned short* __restrict__ out)
{
  __shared__ float t[64][65];
  const int k0 = blockIdx.y * 64;
  const int n0 = blockIdx.x * 64;
  const int tx = threadIdx.x & 63, ty = threadIdx.x >> 6;
#pragma unroll
  for (int r = ty; r < 64; r += 4)
    t[r][tx] = W[(size_t)(k0 + r) * 1024 + n0 + tx];
  __syncthreads();
#pragma unroll
  for (int r = ty; r < 64; r += 4)
    out[(size_t)(n0 + r) * 1024 + k0 + tx] = f2bf(t[tx][r]);
}

// w21[f] = sum_n W2[f][n] * b1[n]   (fp32, one wave per f)
__global__ __launch_bounds__(256)
void w21_kernel(const float* __restrict__ W2, const float* __restrict__ b1,
                float* __restrict__ w21)
{
  const int f = blockIdx.x * 4 + (threadIdx.x >> 6);
  const int lane = threadIdx.x & 63;
  float acc = 0.f;
#pragma unroll 4
  for (int i = 0; i < 16; ++i) {
    const int n = i * 64 + lane;
    acc += W2[(size_t)f * 1024 + n] * b1[n];
  }
#pragma unroll
  for (int o = 32; o; o >>= 1) acc += __shfl_xor(acc, o);
  if (lane == 0) w21[f] = acc;
}

// v[i] = sum_k xb[i*1024+k] * w21[k]   (one wave per row i)
__global__ __launch_bounds__(256)
void v_kernel(const unsigned short* __restrict__ xb, const float* __restrict__ w21,
              float* __restrict__ v)
{
  const int i = blockIdx.x * 4 + (threadIdx.x >> 6);
  const int lane = threadIdx.x & 63;
  float acc = 0.f;
  const unsigned short* row = xb + (size_t)i * 1024;
#pragma unroll 2
  for (int it = 0; it < 2; ++it) {
    const int k0 = (it * 64 + lane) * 8;
    bf16x8 pk = *(const bf16x8*)(row + k0);
#pragma unroll
    for (int j = 0; j < 8; ++j)
      acc += bf2f(((const unsigned short*)&pk)[j]) * w21[k0 + j];
  }
#pragma unroll
  for (int o = 32; o; o >>= 1) acc += __shfl_xor(acc, o);
  if (lane == 0) v[i] = acc;
}

// bf[e] = b4[e] + sum_j b3[j] * W4t[e][j]
__global__ __launch_bounds__(256)
void bias_fold_kernel(const unsigned short* __restrict__ W4t,
                      const float* __restrict__ b3,
                      const float* __restrict__ b4,
                      float* __restrict__ bf)
{
  const int e = blockIdx.x * 4 + (threadIdx.x >> 6);
  const int lane = threadIdx.x & 63;
  float acc = 0.f;
#pragma unroll 4
  for (int i = 0; i < 16; ++i) {
    const int j = i * 64 + lane;
    acc += bf2f(W4t[(size_t)e * 1024 + j]) * b3[j];
  }
#pragma unroll
  for (int o = 32; o; o >>= 1) acc += __shfl_xor(acc, o);
  if (lane == 0) bf[e] = acc + b4[e];
}

// ---------------------------------------------------------------------------
extern "C" void kernel_launch(void* const* d_in, const int* in_sizes, int n_in,
                              void* d_out, int out_size, void* d_ws, size_t ws_size,
                              hipStream_t stream)
{
  const float* x  = (const float*)d_in[0];
  const float* W1 = (const float*)d_in[1];
  const float* b1 = (const float*)d_in[2];
  const float* W2 = (const float*)d_in[3];
  // b2 unused: cancels in softmax (row-constant terms)
  const float* W3 = (const float*)d_in[5];
  const float* b3 = (const float*)d_in[6];
  const float* W4 = (const float*)d_in[7];
  const float* b4 = (const float*)d_in[8];

  char* ws = (char*)d_ws;
  const size_t MB = 1024 * 1024;
  unsigned short* xb    = (unsigned short*)(ws);            // 16MB, alive thru scores
  unsigned short* W4t   = (unsigned short*)(ws + 16 * MB);  // 2MB
  unsigned short* W2b   = (unsigned short*)(ws + 18 * MB);  // 2MB
  unsigned short* W1b   = (unsigned short*)(ws + 20 * MB);  // 2MB
  unsigned short* W3b   = (unsigned short*)(ws + 22 * MB);  // 2MB
  unsigned short* G     = (unsigned short*)(ws + 24 * MB);  // 16MB: x @ M
  unsigned short* MWtb  = (unsigned short*)(ws + 40 * MB);  // 4MB: Mtb | W34tb
  float*          MWf   = (float*)(ws + 44 * MB);           // 8MB fp32 prep acc
  float*          bfv   = (float*)(ws + 52 * MB);           // 4KB
  float*          w21   = (float*)(ws + 52 * MB + 8192);    // 4KB
  float*          vvec  = (float*)(ws + 52 * MB + 16384);   // 32KB
  unsigned short* Vt    = (unsigned short*)(ws + 56 * MB);  // 16MB
  unsigned short* S     = (unsigned short*)(ws + 72 * MB);  // 32MB exp values
  float*          rsum  = MWf;                              // 32KB (dead after MWtb convert)

  unsigned short* Mtb   = MWtb;
  unsigned short* W34tb = MWtb + 1048576;

  convert_kernel<<<4096, 256, 0, stream>>>(x, xb);
  convert3_kernel<<<dim3(512, 3), 256, 0, stream>>>(W1, W2, W3, W1b, W2b, W3b);
  transpose_w4_kernel<<<dim3(16, 16), 256, 0, stream>>>(W4, W4t);

  // Mt = W2b @ W1b^T ; W34 = W4t @ W3b^T  (fp32 split-K, one launch)
  hipMemsetAsync(MWf, 0, 2 * 1024 * 1024 * sizeof(float), stream);
  prep_gemm<<<dim3(8, 8, 8), 256, 0, stream>>>(W2b, W1b, W4t, W3b, MWf);
  convert_kernel<<<1024, 256, 0, stream>>>(MWf, MWtb);

  w21_kernel<<<256, 256, 0, stream>>>(W2, b1, w21);
  bias_fold_kernel<<<256, 256, 0, stream>>>(W4t, b3, b4, bfv);

  // G = xb @ Mtb^T   [8192][1024]                          (256 blocks)
  gemm256<128, 0, false><<<dim3(8, 32, 1), 512, 0, stream>>>(
      xb, Mtb, nullptr, nullptr, G, 1024, 1024, 1024, 1024, 1.f, 0, 0, 0);

  // Vt[z][e][t] = sum_k W34tb[e][k] * xb[z][t][k]          (256 blocks)
  gemm256<128, 0, false><<<dim3(16, 4, 4), 512, 0, stream>>>(
      W34tb, xb, nullptr, nullptr, Vt, 1024, 1024, 1024, 2048, 1.f,
      0, 2048L * 1024, 1024L * 2048);

  // v[i] = xb[i] . w21
  v_kernel<<<2048, 256, 0, stream>>>(xb, w21, vvec);

  // rsum aliases MWf (dead after MWtb convert); zero before scores
  hipMemsetAsync(rsum, 0, 4 * 2048 * sizeof(float), stream);

  // S[z] = exp((G[z] @ xb[z]^T + v[col]) / 32), rowsum -> rsum  (256 blocks)
  gemm256<256, 3, false><<<dim3(8, 8, 4), 512, 0, stream>>>(
      G, xb, vvec, rsum, S, 1024, 1024, 1024, 2048, 0.03125f,
      2048L * 1024, 2048L * 1024, 2048L * 2048);

  // out[z] = (S[z] @ V'[z]) * rcp(rsum[row]) + bfv[col]  (fp32, 256 blocks)
  gemm256<128, 5, true><<<dim3(8, 8, 4), 512, 0, stream>>>(
      S, Vt, bfv, rsum, d_out, 2048, 2048, 2048, 1024, 1.f,
      2048L * 2048, 1024L * 2048, 2048L * 1024);
}

// Round 7
// 184.812 us; speedup vs baseline: 1.1151x; 1.1151x over previous
//
#include <hip/hip_runtime.h>
#include <hip/hip_bf16.h>

typedef __attribute__((ext_vector_type(4))) float f32x4;
typedef __attribute__((ext_vector_type(8))) short bf16x8;

__device__ __forceinline__ void gload_lds16(const void* g, void* l) {
  __builtin_amdgcn_global_load_lds(
      (const __attribute__((address_space(1))) void*)g,
      (__attribute__((address_space(3))) void*)l, 16, 0, 0);
}

__device__ __forceinline__ unsigned short f2bf(float f) {
  union { float f; unsigned u; } x; x.f = f;
  unsigned r = x.u + 0x7fffu + ((x.u >> 16) & 1u);
  return (unsigned short)(r >> 16);
}

__device__ __forceinline__ float bf2f(unsigned short s) {
  union { unsigned u; float f; } x; x.u = (unsigned)s << 16;
  return x.f;
}

template<int N> __device__ __forceinline__ void vm_wait();
template<> __device__ __forceinline__ void vm_wait<0>() { asm volatile("s_waitcnt vmcnt(0)" ::: "memory"); }
template<> __device__ __forceinline__ void vm_wait<4>() { asm volatile("s_waitcnt vmcnt(4)" ::: "memory"); }
template<> __device__ __forceinline__ void vm_wait<6>() { asm volatile("s_waitcnt vmcnt(6)" ::: "memory"); }

#define BARRIER() asm volatile("s_barrier" ::: "memory")
#define SCHED0()  __builtin_amdgcn_sched_barrier(0)

// ---------------------------------------------------------------------------
// 256xBN 8-phase double-buffered GEMM: C = f(alpha * A[M][K] @ Bt[N][K]^T)
// EPI: 0 = alpha only,
//      3 = exp(alpha*(acc + bias[bz*2048+col])) + atomic per-row sum into rs,
//      5 = acc * rcp(rs[row]) + bias[col].
// 512 threads, BK=64, T1 XCD swizzle, T2 LDS swizzle, T4 counted vmcnt, T5.
// ---------------------------------------------------------------------------
template<int BN, int EPI, bool OUT_F32>
__global__ __launch_bounds__(512, 2)
void gemm256(const unsigned short* __restrict__ A,
             const unsigned short* __restrict__ Bt,
             const float* __restrict__ bias,
             float* __restrict__ rs,
             void* __restrict__ Cout,
             int K, int lda, int ldb, int ldc, float alpha,
             long sA, long sB, long sC)
{
  constexpr int THREADS = 512;
  constexpr int WN = BN / 64;          // waves along N (4 or 2)
  constexpr int WM = 8 / WN;           // waves along M (2 or 4)
  constexpr int WTM = 256 / WM;        // wave M extent (128 or 64)
  constexpr int M_REP = WTM / 16;      // 8 or 4
  constexpr int MH = M_REP / 2;        // 4 or 2
  constexpr int ABUFE = 256 * 64;
  constexpr int BBUFE = BN * 64;
  constexpr int BBASE = 2 * ABUFE;
  constexpr int LOADS_A = 2;
  constexpr int LOADS_B = BN / 128;
  constexpr int VM_STEADY = 2 * LOADS_B + LOADS_A;  // 6 or 4

  __shared__ __attribute__((aligned(16))) unsigned short lds[BBASE + 2 * BBUFE];

  // bijective XCD-chunked swizzle
  const int gx = gridDim.x, gy = gridDim.y;
  const int lid = blockIdx.x + gx * (blockIdx.y + gy * blockIdx.z);
  const int nwg = gx * gy * gridDim.z;
  const int q = nwg >> 3, r = nwg & 7;
  const int xcd = lid & 7, idx = lid >> 3;
  const int nl = (xcd < r ? xcd * (q + 1) : r * (q + 1) + (xcd - r) * q) + idx;
  const int bx = nl % gx, by = (nl / gx) % gy, bz = nl / (gx * gy);

  const int tid = threadIdx.x, wave = tid >> 6, lane = tid & 63;
  const int wr = wave / WN, wc = wave % WN;
  const int fr = lane & 15, fq = lane >> 4, sw = fr & 7;

  A  += (size_t)bz * sA;
  Bt += (size_t)bz * sB;
  const int m0 = by * 256;
  const int n0 = bx * BN;
  const int NT = K >> 6;

  f32x4 acc[M_REP][4] = {};
  bf16x8 a[MH][2], b[4][2];

  auto stageA = [&](int t, int half) {
#pragma unroll
    for (int c = 0; c < LOADS_A; ++c) {
      const int s = c * THREADS + tid;
      const int rr = s >> 3;
      const int col = ((tid & 7) ^ (rr & 7)) * 8;
      gload_lds16(A + (size_t)(m0 + half * 128 + rr) * lda + t * 64 + col,
                  &lds[(t & 1) * ABUFE + half * (128 * 64) + s * 8]);
    }
  };
  auto stageB = [&](int t, int half) {
#pragma unroll
    for (int c = 0; c < LOADS_B; ++c) {
      const int s = c * THREADS + tid;
      const int rr = s >> 3;
      const int col = ((tid & 7) ^ (rr & 7)) * 8;
      gload_lds16(Bt + (size_t)(n0 + half * (BN / 2) + rr) * ldb + t * 64 + col,
                  &lds[BBASE + (t & 1) * BBUFE + half * ((BN / 2) * 64) + s * 8]);
    }
  };
  auto readA = [&](int buf, int mq) {
    const unsigned short* p = &lds[buf * ABUFE];
#pragma unroll
    for (int mm = 0; mm < MH; ++mm)
#pragma unroll
      for (int kk = 0; kk < 2; ++kk)
        a[mm][kk] = *(const bf16x8*)(p + (wr * WTM + mq * (WTM / 2) + mm * 16 + fr) * 64
                                       + ((kk * 4 + fq) ^ sw) * 8);
  };
  auto readB = [&](int buf, int nh) {
    const unsigned short* p = &lds[BBASE + buf * BBUFE];
#pragma unroll
    for (int nn = 0; nn < 2; ++nn)
#pragma unroll
      for (int kk = 0; kk < 2; ++kk)
        b[nh * 2 + nn][kk] = *(const bf16x8*)(p + (wc * 64 + (nh * 2 + nn) * 16 + fr) * 64
                                                + ((kk * 4 + fq) ^ sw) * 8);
  };
  auto mfmaQ = [&](int mq, int nh) {
    __builtin_amdgcn_s_setprio(1);
#pragma unroll
    for (int kk = 0; kk < 2; ++kk)
#pragma unroll
      for (int mm = 0; mm < MH; ++mm)
#pragma unroll
        for (int nn = 0; nn < 2; ++nn)
          acc[mq * MH + mm][nh * 2 + nn] = __builtin_amdgcn_mfma_f32_16x16x32_bf16(
              a[mm][kk], b[nh * 2 + nn][kk], acc[mq * MH + mm][nh * 2 + nn], 0, 0, 0);
    __builtin_amdgcn_s_setprio(0);
  };

  // prologue: tile0 fully, tile1 {B0,B1,A0}
  stageA(0, 0); stageA(0, 1); stageB(0, 0); stageB(0, 1);
  if (NT > 1) { stageB(1, 0); stageB(1, 1); stageA(1, 0); vm_wait<VM_STEADY>(); }
  else        { vm_wait<0>(); }
  BARRIER();

  for (int t = 0; t < NT; ++t) {
    const int buf = t & 1;
    // ph1
    readA(buf, 0); readB(buf, 0);
    BARRIER(); SCHED0();
    mfmaQ(0, 0);
    SCHED0();
    BARRIER();
    // ph2
    readB(buf, 1);
    if (t + 1 < NT) stageA(t + 1, 1);
    BARRIER(); SCHED0();
    mfmaQ(0, 1);
    SCHED0();
    BARRIER();
    // ph3
    readA(buf, 1);
    if (t + 2 < NT) stageB(t + 2, 0);
    BARRIER(); SCHED0();
    mfmaQ(1, 0);
    SCHED0();
    BARRIER();
    // ph4
    if (t + 2 < NT) { stageB(t + 2, 1); stageA(t + 2, 0); vm_wait<VM_STEADY>(); }
    else            { vm_wait<0>(); }
    BARRIER(); SCHED0();
    mfmaQ(1, 1);
    SCHED0();
    BARRIER();
  }

  // epilogue (nn innermost for L2 write combining)
  float bvc[4];
  if (EPI == 5) {
#pragma unroll
    for (int nn = 0; nn < 4; ++nn) bvc[nn] = bias[n0 + wc * 64 + nn * 16 + fr];
  }
  if (EPI == 3) {
#pragma unroll
    for (int nn = 0; nn < 4; ++nn)
      bvc[nn] = bias[(size_t)bz * 2048 + n0 + wc * 64 + nn * 16 + fr];
  }
#pragma unroll
  for (int mm = 0; mm < M_REP; ++mm) {
    const int rbase = m0 + wr * WTM + mm * 16 + fq * 4;
#pragma unroll
    for (int j = 0; j < 4; ++j) {
      const int row = rbase + j;
      float rsc = 1.f;
      if (EPI == 5) rsc = __builtin_amdgcn_rcpf(rs[(size_t)bz * 2048 + row]);
      float part = 0.f;
#pragma unroll
      for (int nn = 0; nn < 4; ++nn) {
        const int col = n0 + wc * 64 + nn * 16 + fr;
        float v = acc[mm][nn][j];
        if      (EPI == 3) { v = __expf((v + bvc[nn]) * alpha); part += v; }
        else if (EPI == 5) v = v * rsc + bvc[nn];
        else               v = v * alpha;
        const size_t off = (size_t)bz * sC + (size_t)row * ldc + col;
        if (OUT_F32) ((float*)Cout)[off] = v;
        else         ((unsigned short*)Cout)[off] = f2bf(v);
      }
      if (EPI == 3) {
        part += __shfl_xor(part, 1); part += __shfl_xor(part, 2);
        part += __shfl_xor(part, 4); part += __shfl_xor(part, 8);
        if (fr == 0) atomicAdd(rs + (size_t)bz * 2048 + row, part);
      }
    }
  }
}

// ---------------------------------------------------------------------------
// prep GEMM (no atomics, full K=1024, bf16 out): z=0: Mtb = W2b @ W1b^T,
// z=1: W34tb = W4t @ W3b^T. 128^2 tile, 4 waves, BK=32 (m97 structure).
// ---------------------------------------------------------------------------
__global__ __launch_bounds__(256, 2)
void prep_gemm(const unsigned short* __restrict__ W2b, const unsigned short* __restrict__ W1b,
               const unsigned short* __restrict__ W4t, const unsigned short* __restrict__ W3b,
               unsigned short* __restrict__ Mtb, unsigned short* __restrict__ W34tb)
{
  __shared__ __attribute__((aligned(16))) unsigned short As[128 * 32];
  __shared__ __attribute__((aligned(16))) unsigned short Bs[128 * 32];
  const int which = blockIdx.z;
  const unsigned short* A  = which ? W4t : W2b;
  const unsigned short* Bt = which ? W3b : W1b;
  unsigned short* C = which ? W34tb : Mtb;

  const int tid = threadIdx.x, wave = tid >> 6, lane = tid & 63;
  const int m0 = blockIdx.y * 128, n0 = blockIdx.x * 128;
  f32x4 acc[4][4] = {};
  const int wr = wave >> 1, wc = wave & 1;
  const int fr = lane & 15, fq = lane >> 4;
  const int si0 = wave * 2, sr = lane >> 2, sce = (lane & 3) * 8;

  for (int k0 = 0; k0 < 1024; k0 += 32) {
#pragma unroll
    for (int c = 0; c < 2; ++c) {
      const int i = si0 + c, rr = i * 16 + sr;
      gload_lds16(A  + (size_t)(m0 + rr) * 1024 + k0 + sce, As + i * 512 + lane * 8);
      gload_lds16(Bt + (size_t)(n0 + rr) * 1024 + k0 + sce, Bs + i * 512 + lane * 8);
    }
    __syncthreads();
    bf16x8 af[4], bg[4];
#pragma unroll
    for (int m = 0; m < 4; ++m)
      af[m] = *(const bf16x8*)(As + (wr * 64 + m * 16 + fr) * 32 + fq * 8);
#pragma unroll
    for (int n = 0; n < 4; ++n)
      bg[n] = *(const bf16x8*)(Bs + (wc * 64 + n * 16 + fr) * 32 + fq * 8);
#pragma unroll
    for (int m = 0; m < 4; ++m)
#pragma unroll
      for (int n = 0; n < 4; ++n)
        acc[m][n] = __builtin_amdgcn_mfma_f32_16x16x32_bf16(af[m], bg[n], acc[m][n], 0, 0, 0);
    __syncthreads();
  }
#pragma unroll
  for (int m = 0; m < 4; ++m) {
    const int rbase = m0 + wr * 64 + m * 16 + fq * 4;
#pragma unroll
    for (int j = 0; j < 4; ++j)
#pragma unroll
      for (int n = 0; n < 4; ++n) {
        const int col = n0 + wc * 64 + n * 16 + fr;
        C[(size_t)(rbase + j) * 1024 + col] = f2bf(acc[m][n][j]);
      }
  }
}

// ---------------------------------------------------------------------------
// fp32 -> bf16 straight convert, 2048 elements per block
__global__ __launch_bounds__(256)
void convert_kernel(const float* __restrict__ x, unsigned short* __restrict__ xb)
{
  const int idx = (blockIdx.x * 256 + threadIdx.x) * 8;
  const float4 a = *(const float4*)(x + idx);
  const float4 b = *(const float4*)(x + idx + 4);
  unsigned u0 = (unsigned)f2bf(a.x) | ((unsigned)f2bf(a.y) << 16);
  unsigned u1 = (unsigned)f2bf(a.z) | ((unsigned)f2bf(a.w) << 16);
  unsigned u2 = (unsigned)f2bf(b.x) | ((unsigned)f2bf(b.y) << 16);
  unsigned u3 = (unsigned)f2bf(b.z) | ((unsigned)f2bf(b.w) << 16);
  uint4 o; o.x = u0; o.y = u1; o.z = u2; o.w = u3;
  *(uint4*)(xb + idx) = o;
}

// three 1024x1024 fp32 -> bf16 converts in one launch
__global__ __launch_bounds__(256)
void convert3_kernel(const float* __restrict__ a, const float* __restrict__ b,
                     const float* __restrict__ c,
                     unsigned short* __restrict__ oa, unsigned short* __restrict__ ob,
                     unsigned short* __restrict__ oc)
{
  const float* src = (blockIdx.y == 0) ? a : (blockIdx.y == 1) ? b : c;
  unsigned short* dst = (blockIdx.y == 0) ? oa : (blockIdx.y == 1) ? ob : oc;
  const int idx = (blockIdx.x * 256 + threadIdx.x) * 8;
  const float4 p = *(const float4*)(src + idx);
  const float4 q = *(const float4*)(src + idx + 4);
  unsigned u0 = (unsigned)f2bf(p.x) | ((unsigned)f2bf(p.y) << 16);
  unsigned u1 = (unsigned)f2bf(p.z) | ((unsigned)f2bf(p.w) << 16);
  unsigned u2 = (unsigned)f2bf(q.x) | ((unsigned)f2bf(q.y) << 16);
  unsigned u3 = (unsigned)f2bf(q.z) | ((unsigned)f2bf(q.w) << 16);
  uint4 o; o.x = u0; o.y = u1; o.z = u2; o.w = u3;
  *(uint4*)(dst + idx) = o;
}

// W4 fp32 [1024][1024] (j-major) -> W4t bf16 [1024][1024] (e-major)
__global__ __launch_bounds__(256)
void transpose_w4_kernel(const float* __restrict__ W, unsigned short* __restrict__ out)
{
  __shared__ float t[64][65];
  const int k0 = blockIdx.y * 64;
  const int n0 = blockIdx.x * 64;
  const int tx = threadIdx.x & 63, ty = threadIdx.x >> 6;
#pragma unroll
  for (int r = ty; r < 64; r += 4)
    t[r][tx] = W[(size_t)(k0 + r) * 1024 + n0 + tx];
  __syncthreads();
#pragma unroll
  for (int r = ty; r < 64; r += 4)
    out[(size_t)(n0 + r) * 1024 + k0 + tx] = f2bf(t[tx][r]);
}

// y==0: w21[f] = sum_n W2[f][n]*b1[n];  y==1: bfv[e] = b4[e] + sum_j b3[j]*W4t[e][j]
__global__ __launch_bounds__(256)
void prep_vec_kernel(const float* __restrict__ W2, const float* __restrict__ b1,
                     const unsigned short* __restrict__ W4t,
                     const float* __restrict__ b3, const float* __restrict__ b4,
                     float* __restrict__ w21, float* __restrict__ bfv)
{
  const int e = blockIdx.x * 4 + (threadIdx.x >> 6);
  const int lane = threadIdx.x & 63;
  float acc = 0.f;
  if (blockIdx.y == 0) {
#pragma unroll 4
    for (int i = 0; i < 16; ++i) {
      const int n = i * 64 + lane;
      acc += W2[(size_t)e * 1024 + n] * b1[n];
    }
#pragma unroll
    for (int o = 32; o; o >>= 1) acc += __shfl_xor(acc, o);
    if (lane == 0) w21[e] = acc;
  } else {
#pragma unroll 4
    for (int i = 0; i < 16; ++i) {
      const int j = i * 64 + lane;
      acc += bf2f(W4t[(size_t)e * 1024 + j]) * b3[j];
    }
#pragma unroll
    for (int o = 32; o; o >>= 1) acc += __shfl_xor(acc, o);
    if (lane == 0) bfv[e] = acc + b4[e];
  }
}

// v[i] = sum_k xb[i*1024+k] * w21[k]   (one wave per row i)
__global__ __launch_bounds__(256)
void v_kernel(const unsigned short* __restrict__ xb, const float* __restrict__ w21,
              float* __restrict__ v)
{
  const int i = blockIdx.x * 4 + (threadIdx.x >> 6);
  const int lane = threadIdx.x & 63;
  float acc = 0.f;
  const unsigned short* row = xb + (size_t)i * 1024;
#pragma unroll 2
  for (int it = 0; it < 2; ++it) {
    const int k0 = (it * 64 + lane) * 8;
    bf16x8 pk = *(const bf16x8*)(row + k0);
#pragma unroll
    for (int j = 0; j < 8; ++j)
      acc += bf2f(((const unsigned short*)&pk)[j]) * w21[k0 + j];
  }
#pragma unroll
  for (int o = 32; o; o >>= 1) acc += __shfl_xor(acc, o);
  if (lane == 0) v[i] = acc;
}

// ---------------------------------------------------------------------------
extern "C" void kernel_launch(void* const* d_in, const int* in_sizes, int n_in,
                              void* d_out, int out_size, void* d_ws, size_t ws_size,
                              hipStream_t stream)
{
  const float* x  = (const float*)d_in[0];
  const float* W1 = (const float*)d_in[1];
  const float* b1 = (const float*)d_in[2];
  const float* W2 = (const float*)d_in[3];
  // b2 unused: cancels in softmax (row-constant terms)
  const float* W3 = (const float*)d_in[5];
  const float* b3 = (const float*)d_in[6];
  const float* W4 = (const float*)d_in[7];
  const float* b4 = (const float*)d_in[8];

  char* ws = (char*)d_ws;
  const size_t MB = 1024 * 1024;
  unsigned short* xb    = (unsigned short*)(ws);            // 16MB, alive thru scores
  unsigned short* W4t   = (unsigned short*)(ws + 16 * MB);  // 2MB
  unsigned short* W2b   = (unsigned short*)(ws + 18 * MB);  // 2MB
  unsigned short* W1b   = (unsigned short*)(ws + 20 * MB);  // 2MB
  unsigned short* W3b   = (unsigned short*)(ws + 22 * MB);  // 2MB
  unsigned short* G     = (unsigned short*)(ws + 24 * MB);  // 16MB: x @ M
  unsigned short* Mtb   = (unsigned short*)(ws + 40 * MB);  // 2MB
  unsigned short* W34tb = (unsigned short*)(ws + 42 * MB);  // 2MB
  float*          rsum  = (float*)(ws + 44 * MB);           // 32KB
  float*          bfv   = (float*)(ws + 45 * MB);           // 4KB
  float*          w21   = (float*)(ws + 45 * MB + 8192);    // 4KB
  float*          vvec  = (float*)(ws + 45 * MB + 16384);   // 32KB
  unsigned short* Vt    = (unsigned short*)(ws + 56 * MB);  // 16MB
  unsigned short* S     = (unsigned short*)(ws + 72 * MB);  // 32MB exp values

  convert_kernel<<<4096, 256, 0, stream>>>(x, xb);
  convert3_kernel<<<dim3(512, 3), 256, 0, stream>>>(W1, W2, W3, W1b, W2b, W3b);
  transpose_w4_kernel<<<dim3(16, 16), 256, 0, stream>>>(W4, W4t);

  // Mtb = W2b @ W1b^T ; W34tb = W4t @ W3b^T  (bf16 out, no atomics)
  prep_gemm<<<dim3(8, 8, 2), 256, 0, stream>>>(W2b, W1b, W4t, W3b, Mtb, W34tb);

  prep_vec_kernel<<<dim3(256, 2), 256, 0, stream>>>(W2, b1, W4t, b3, b4, w21, bfv);

  // G = xb @ Mtb^T   [8192][1024]                          (256 blocks)
  gemm256<128, 0, false><<<dim3(8, 32, 1), 512, 0, stream>>>(
      xb, Mtb, nullptr, nullptr, G, 1024, 1024, 1024, 1024, 1.f, 0, 0, 0);

  // Vt[z][e][t] = sum_k W34tb[e][k] * xb[z][t][k]          (256 blocks)
  gemm256<128, 0, false><<<dim3(16, 4, 4), 512, 0, stream>>>(
      W34tb, xb, nullptr, nullptr, Vt, 1024, 1024, 1024, 2048, 1.f,
      0, 2048L * 1024, 1024L * 2048);

  // v[i] = xb[i] . w21
  v_kernel<<<2048, 256, 0, stream>>>(xb, w21, vvec);

  hipMemsetAsync(rsum, 0, 4 * 2048 * sizeof(float), stream);

  // S[z] = exp((G[z] @ xb[z]^T + v[col]) / 32), rowsum -> rsum  (256 blocks)
  gemm256<256, 3, false><<<dim3(8, 8, 4), 512, 0, stream>>>(
      G, xb, vvec, rsum, S, 1024, 1024, 1024, 2048, 0.03125f,
      2048L * 1024, 2048L * 1024, 2048L * 2048);

  // out[z] = (S[z] @ V'[z]) * rcp(rsum[row]) + bfv[col]  (fp32, 256 blocks)
  gemm256<128, 5, true><<<dim3(8, 8, 4), 512, 0, stream>>>(
      S, Vt, bfv, rsum, d_out, 2048, 2048, 2048, 1024, 1.f,
      2048L * 2048, 1024L * 2048, 2048L * 1024);
}